// Round 1
// baseline (3448.976 us; speedup 1.0000x reference)
//
#include <hip/hip_runtime.h>
#include <math.h>

#define BB 8
#define CC 256
#define NTOK 2304   // 48*48

#define LOG2E 1.4426950408889634f

// ---------------- projection ----------------
// Per batch: Y[n][d] = sum_c X[c][n] * W[d][c]
// TRANS=false: store Y as [NTOK][CC]; TRANS=true: store Y^T as [CC][NTOK]
template<bool TRANS>
__global__ __launch_bounds__(256)
void proj_kernel(const float* __restrict__ X, const float* __restrict__ W,
                 float* __restrict__ Y) {
  const int n0 = blockIdx.x * 64;
  const int d0 = blockIdx.y * 64;
  const int b  = blockIdx.z;
  const float* Xb = X + (size_t)b * CC * NTOK;
  float* Yb = Y + (size_t)b * CC * NTOK;

  __shared__ float Wt[32][68];   // Wt[c][d]
  __shared__ float Xs[32][68];   // Xs[c][n]

  const int t  = threadIdx.x;
  const int tn = t & 15;         // 0..15 -> n sub
  const int td = t >> 4;         // 0..15 -> d sub

  float acc[4][4];
  #pragma unroll
  for (int i = 0; i < 4; i++)
    #pragma unroll
    for (int j = 0; j < 4; j++) acc[i][j] = 0.f;

  for (int c0 = 0; c0 < CC; c0 += 32) {
    // load W tile (transposed into LDS): Wt[c][d] = W[(d0+d)*CC + c0+c]
    {
      const int c = t & 31, dr = t >> 5;   // dr 0..7
      #pragma unroll
      for (int j = 0; j < 8; j++) {
        int d = dr + 8 * j;
        Wt[c][d] = W[(size_t)(d0 + d) * CC + c0 + c];
      }
    }
    // load X tile: Xs[c][n] = Xb[(c0+c)*NTOK + n0+n]
    {
      const int n = t & 63, cr = t >> 6;   // cr 0..3
      #pragma unroll
      for (int j = 0; j < 8; j++) {
        int c = cr + 4 * j;
        Xs[c][n] = Xb[(size_t)(c0 + c) * NTOK + n0 + n];
      }
    }
    __syncthreads();
    #pragma unroll
    for (int c = 0; c < 32; c++) {
      float4 wv = *(const float4*)&Wt[c][td * 4];
      float4 xv = *(const float4*)&Xs[c][tn * 4];
      float wf[4] = {wv.x, wv.y, wv.z, wv.w};
      float xf[4] = {xv.x, xv.y, xv.z, xv.w};
      #pragma unroll
      for (int i = 0; i < 4; i++)
        #pragma unroll
        for (int j = 0; j < 4; j++)
          acc[i][j] = fmaf(xf[i], wf[j], acc[i][j]);
    }
    __syncthreads();
  }

  if (!TRANS) {
    // Y[n][d], n = n0+tn*4+i, d = d0+td*4+j
    #pragma unroll
    for (int i = 0; i < 4; i++) {
      float4 v = make_float4(acc[i][0], acc[i][1], acc[i][2], acc[i][3]);
      *(float4*)&Yb[(size_t)(n0 + tn * 4 + i) * CC + d0 + td * 4] = v;
    }
  } else {
    // Yt[d][n]
    #pragma unroll
    for (int j = 0; j < 4; j++) {
      float4 v = make_float4(acc[0][j], acc[1][j], acc[2][j], acc[3][j]);
      *(float4*)&Yb[(size_t)(d0 + td * 4 + j) * NTOK + n0 + tn * 4] = v;
    }
  }
}

// ---------------- fused dual-softmax attention ----------------
// Block: 256 threads (4 waves), 32 q-rows (8 per wave).
// K1t/K2t are [CC][NTOK] per batch (transposed); Q,V are [NTOK][CC].
__global__ __launch_bounds__(256)
void attn_kernel(const float* __restrict__ Q, const float* __restrict__ K1t,
                 const float* __restrict__ K2t, const float* __restrict__ V,
                 const float* __restrict__ qry, const float* __restrict__ mup,
                 float* __restrict__ out) {
  const int q0 = blockIdx.x * 32;
  const int b  = blockIdx.y;
  const size_t bo = (size_t)b * CC * NTOK;
  const float* Qb  = Q  + bo;
  const float* K1b = K1t + bo;
  const float* K2b = K2t + bo;
  const float* Vb  = V  + bo;

  __shared__ float Qs[32][260];          // Q tile, reused as att buffer
  __shared__ float plds[4][2][8][64];    // per-wave softmax weights

  const int t = threadIdx.x;
  const int w = t >> 6;    // wave 0..3
  const int l = t & 63;    // lane

  // load Q tile (coalesced)
  #pragma unroll
  for (int j = 0; j < 32; j++) {
    int idx = t + 256 * j;
    int r = idx >> 8, d = idx & 255;
    Qs[r][d] = Qb[(size_t)(q0 + r) * CC + d];
  }
  __syncthreads();

  float m1[8], m2[8], l1[8], l2[8];
  float a1[8][4], a2[8][4];
  #pragma unroll
  for (int r = 0; r < 8; r++) {
    m1[r] = -INFINITY; m2[r] = -INFINITY; l1[r] = 0.f; l2[r] = 0.f;
    #pragma unroll
    for (int j = 0; j < 4; j++) { a1[r][j] = 0.f; a2[r][j] = 0.f; }
  }

  for (int k0 = 0; k0 < NTOK; k0 += 64) {
    // ---- S phase: lane owns k = k0 + l; s[r] = Q[row r] . K[k]
    float s1[8], s2[8];
    #pragma unroll
    for (int r = 0; r < 8; r++) { s1[r] = 0.f; s2[r] = 0.f; }

    for (int d0 = 0; d0 < CC; d0 += 4) {
      float kv1[4], kv2[4];
      #pragma unroll
      for (int j = 0; j < 4; j++) {
        kv1[j] = K1b[(size_t)(d0 + j) * NTOK + k0 + l];
        kv2[j] = K2b[(size_t)(d0 + j) * NTOK + k0 + l];
      }
      #pragma unroll
      for (int r = 0; r < 8; r++) {
        float4 qv = *(const float4*)&Qs[w * 8 + r][d0];
        s1[r] = fmaf(qv.x, kv1[0], s1[r]); s1[r] = fmaf(qv.y, kv1[1], s1[r]);
        s1[r] = fmaf(qv.z, kv1[2], s1[r]); s1[r] = fmaf(qv.w, kv1[3], s1[r]);
        s2[r] = fmaf(qv.x, kv2[0], s2[r]); s2[r] = fmaf(qv.y, kv2[1], s2[r]);
        s2[r] = fmaf(qv.z, kv2[2], s2[r]); s2[r] = fmaf(qv.w, kv2[3], s2[r]);
      }
    }

    // ---- online softmax update (per row, both paths)
    #pragma unroll
    for (int r = 0; r < 8; r++) {
      float mx1 = s1[r], mx2 = s2[r];
      #pragma unroll
      for (int o = 32; o > 0; o >>= 1) {
        mx1 = fmaxf(mx1, __shfl_xor(mx1, o));
        mx2 = fmaxf(mx2, __shfl_xor(mx2, o));
      }
      float nm1 = fmaxf(m1[r], mx1), nm2 = fmaxf(m2[r], mx2);
      float sc1 = exp2f((m1[r] - nm1) * LOG2E);
      float sc2 = exp2f((m2[r] - nm2) * LOG2E);
      float p1 = exp2f((s1[r] - nm1) * LOG2E);
      float p2 = exp2f((s2[r] - nm2) * LOG2E);
      float ps1 = p1, ps2 = p2;
      #pragma unroll
      for (int o = 32; o > 0; o >>= 1) {
        ps1 += __shfl_xor(ps1, o);
        ps2 += __shfl_xor(ps2, o);
      }
      l1[r] = l1[r] * sc1 + ps1;
      l2[r] = l2[r] * sc2 + ps2;
      m1[r] = nm1; m2[r] = nm2;
      #pragma unroll
      for (int j = 0; j < 4; j++) { a1[r][j] *= sc1; a2[r][j] *= sc2; }
      plds[w][0][r][l] = p1;
      plds[w][1][r][l] = p2;
    }
    // wave-local LDS write->read; compiler inserts lgkmcnt waits

    // ---- PV phase: acc[r][d=l+64j] += p[k] * V[k][d]
    for (int kk = 0; kk < 64; kk += 4) {
      float vv[4][4];
      #pragma unroll
      for (int k2 = 0; k2 < 4; k2++)
        #pragma unroll
        for (int j = 0; j < 4; j++)
          vv[k2][j] = Vb[(size_t)(k0 + kk + k2) * CC + l + 64 * j];
      #pragma unroll
      for (int r = 0; r < 8; r++) {
        float4 p1v = *(const float4*)&plds[w][0][r][kk];
        float4 p2v = *(const float4*)&plds[w][1][r][kk];
        float p1f[4] = {p1v.x, p1v.y, p1v.z, p1v.w};
        float p2f[4] = {p2v.x, p2v.y, p2v.z, p2v.w};
        #pragma unroll
        for (int j = 0; j < 4; j++) {
          #pragma unroll
          for (int k2 = 0; k2 < 4; k2++) {
            a1[r][j] = fmaf(p1f[k2], vv[k2][j], a1[r][j]);
            a2[r][j] = fmaf(p2f[k2], vv[k2][j], a2[r][j]);
          }
        }
      }
    }
  }

  // ---- combine paths, stage att tile into LDS (reuse Qs)
  const float mu = mup[0];
  const float cw1 = 0.5f / (0.5f + mu);
  const float cw2 = mu / (0.5f + mu);
  #pragma unroll
  for (int r = 0; r < 8; r++) {
    float i1 = cw1 / l1[r];
    float i2 = cw2 / l2[r];
    #pragma unroll
    for (int j = 0; j < 4; j++)
      Qs[w * 8 + r][l + 64 * j] = a1[r][j] * i1 + a2[r][j] * i2;
  }
  __syncthreads();

  // ---- epilogue: out[b][d][q] = qry[b][d][q] + att[q][d], coalesced over q
  const int qq = t & 31, dr = t >> 5;   // dr 0..7
  #pragma unroll
  for (int i = 0; i < 32; i++) {
    int d = dr + 8 * i;
    size_t gi = bo + (size_t)d * NTOK + q0 + qq;
    out[gi] = qry[gi] + Qs[qq][d];
  }
}

extern "C" void kernel_launch(void* const* d_in, const int* in_sizes, int n_in,
                              void* d_out, int out_size, void* d_ws, size_t ws_size,
                              hipStream_t stream) {
  const float* qry  = (const float*)d_in[0];
  const float* mask = (const float*)d_in[1];
  const float* fts  = (const float*)d_in[2];
  const float* Wq   = (const float*)d_in[3];
  const float* Wk   = (const float*)d_in[4];
  const float* Wv   = (const float*)d_in[5];
  const float* mu   = (const float*)d_in[6];
  float* out = (float*)d_out;
  float* ws  = (float*)d_ws;

  const size_t SZ = (size_t)BB * CC * NTOK;   // 4.72M floats per tensor
  float* Qw  = ws;
  float* K1t = ws + SZ;
  float* K2t = ws + 2 * SZ;
  float* Vw  = ws + 3 * SZ;

  dim3 pg(NTOK / 64, CC / 64, BB);   // 36 x 4 x 8
  proj_kernel<false><<<pg, 256, 0, stream>>>(qry,  Wq, Qw);   // Q  [n][d]
  proj_kernel<true ><<<pg, 256, 0, stream>>>(fts,  Wk, K1t);  // K1 [d][n]
  proj_kernel<true ><<<pg, 256, 0, stream>>>(mask, Wk, K2t);  // K2 [d][n]
  proj_kernel<false><<<pg, 256, 0, stream>>>(fts,  Wv, Vw);   // V  [n][d]

  dim3 ag(NTOK / 32, BB);            // 72 x 8
  attn_kernel<<<ag, 256, 0, stream>>>(Qw, K1t, K2t, Vw, qry, mu, out);
}

// Round 2
// 803.743 us; speedup vs baseline: 4.2911x; 4.2911x over previous
//
#include <hip/hip_runtime.h>
#include <math.h>

#define BB 8
#define CC 256
#define NTOK 2304   // 48*48
#define KVB 32
#define LOG2E 1.4426950408889634f
#define BIAS2 72.134752f   // 50 * log2(e)

typedef __attribute__((ext_vector_type(4))) float f32x4;
typedef __attribute__((ext_vector_type(8))) short s16x8;
typedef __attribute__((ext_vector_type(4))) short s16x4;

__device__ inline unsigned short f2bf(float x) {
  unsigned u = __builtin_bit_cast(unsigned, x);
  return (unsigned short)((u + 0x7FFFu + ((u >> 16) & 1u)) >> 16);
}
__device__ inline float bf2f(unsigned short h) {
  return __builtin_bit_cast(float, (unsigned)h << 16);
}

// ---------------- projection ----------------
// Per batch: Y[n][d] = sum_c X[c][n] * W[d][c]   (fp32 accumulate)
// MODE 0: write Qh,Ql bf16 [n][d], scaled by LOG2E (split hi/lo)
// MODE 1: write Kh bf16 [n][d]
// MODE 2: write V^T bf16 [d][n]
template<int MODE>
__global__ __launch_bounds__(256)
void proj_kernel(const float* __restrict__ X, const float* __restrict__ W,
                 unsigned short* __restrict__ Y0, unsigned short* __restrict__ Y1) {
  const int n0 = blockIdx.x * 64;
  const int d0 = blockIdx.y * 64;
  const int b  = blockIdx.z;
  const float* Xb = X + (size_t)b * CC * NTOK;
  unsigned short* Yb0 = Y0 + (size_t)b * CC * NTOK;
  unsigned short* Yb1 = (MODE == 0) ? (Y1 + (size_t)b * CC * NTOK) : nullptr;

  __shared__ float Wt[32][68];   // Wt[c][d]
  __shared__ float Xs[32][68];   // Xs[c][n]

  const int t  = threadIdx.x;
  const int tn = t & 15;
  const int td = t >> 4;

  float acc[4][4];
  #pragma unroll
  for (int i = 0; i < 4; i++)
    #pragma unroll
    for (int j = 0; j < 4; j++) acc[i][j] = 0.f;

  for (int c0 = 0; c0 < CC; c0 += 32) {
    {
      const int c = t & 31, dr = t >> 5;
      #pragma unroll
      for (int j = 0; j < 8; j++) {
        int d = dr + 8 * j;
        Wt[c][d] = W[(size_t)(d0 + d) * CC + c0 + c];
      }
    }
    {
      const int n = t & 63, cr = t >> 6;
      #pragma unroll
      for (int j = 0; j < 8; j++) {
        int c = cr + 4 * j;
        Xs[c][n] = Xb[(size_t)(c0 + c) * NTOK + n0 + n];
      }
    }
    __syncthreads();
    #pragma unroll
    for (int c = 0; c < 32; c++) {
      float4 wv = *(const float4*)&Wt[c][td * 4];
      float4 xv = *(const float4*)&Xs[c][tn * 4];
      float wf[4] = {wv.x, wv.y, wv.z, wv.w};
      float xf[4] = {xv.x, xv.y, xv.z, xv.w};
      #pragma unroll
      for (int i = 0; i < 4; i++)
        #pragma unroll
        for (int j = 0; j < 4; j++)
          acc[i][j] = fmaf(xf[i], wf[j], acc[i][j]);
    }
    __syncthreads();
  }

  if (MODE == 0) {
    #pragma unroll
    for (int i = 0; i < 4; i++) {
      s16x4 hv, lv;
      #pragma unroll
      for (int j = 0; j < 4; j++) {
        float v = acc[i][j] * LOG2E;
        unsigned short h = f2bf(v);
        hv[j] = (short)h;
        lv[j] = (short)f2bf(v - bf2f(h));
      }
      int n = n0 + tn * 4 + i, d = d0 + td * 4;
      *(s16x4*)&Yb0[(size_t)n * CC + d] = hv;
      *(s16x4*)&Yb1[(size_t)n * CC + d] = lv;
    }
  } else if (MODE == 1) {
    #pragma unroll
    for (int i = 0; i < 4; i++) {
      s16x4 hv;
      #pragma unroll
      for (int j = 0; j < 4; j++) hv[j] = (short)f2bf(acc[i][j]);
      int n = n0 + tn * 4 + i, d = d0 + td * 4;
      *(s16x4*)&Yb0[(size_t)n * CC + d] = hv;
    }
  } else {
    #pragma unroll
    for (int j = 0; j < 4; j++) {
      s16x4 v;
      #pragma unroll
      for (int i = 0; i < 4; i++) v[i] = (short)f2bf(acc[i][j]);
      int d = d0 + td * 4 + j, n = n0 + tn * 4;
      *(s16x4*)&Yb0[(size_t)d * NTOK + n] = v;
    }
  }
}

// ---------------- fused dual-softmax MFMA attention ----------------
// 4 waves, 64 q-rows/block (16/wave), KVB=32 keys per tile.
// Qh/Ql/K1h/K2h bf16 [n][d]; Vt bf16 [d][n]. No-max softmax: p = 2^(s - BIAS2).
__global__ __launch_bounds__(256, 2)
void attn_kernel(const unsigned short* __restrict__ Qh, const unsigned short* __restrict__ Ql,
                 const unsigned short* __restrict__ K1h, const unsigned short* __restrict__ K2h,
                 const unsigned short* __restrict__ Vt, const float* __restrict__ qry,
                 const float* __restrict__ mup, float* __restrict__ out) {
  __shared__ alignas(16) char smem[68608];
  const int K1O = 0, K2O = 16384, VO = 32768, PO = 50176;

  const int t = threadIdx.x;
  const int w = t >> 6, l = t & 63, g = l >> 4, c = l & 15;
  const int bid = blockIdx.x;
  const int b = bid & 7, qt = bid >> 3;        // batch -> XCD pinning
  const int q0 = qt * 64, qw0 = q0 + w * 16;
  const size_t bo = (size_t)b * CC * NTOK;

  const char* Qhb = (const char*)(Qh + bo);
  const char* Qlb = (const char*)(Ql + bo);
  const char* K1b = (const char*)(K1h + bo);
  const char* K2b = (const char*)(K2h + bo);
  const char* Vtb = (const char*)(Vt + bo);

  // Q fragments resident in registers (A-operand: row=c, k=g*8+j within 32-chunk)
  s16x8 qh[8], ql[8];
  #pragma unroll
  for (int dc = 0; dc < 8; dc++) {
    int off = (qw0 + c) * 512 + dc * 64 + g * 16;
    qh[dc] = *(const s16x8*)(Qhb + off);
    ql[dc] = *(const s16x8*)(Qlb + off);
  }

  f32x4 a1[16], a2[16];
  #pragma unroll
  for (int dt = 0; dt < 16; dt++) {
    a1[dt] = (f32x4){0.f, 0.f, 0.f, 0.f};
    a2[dt] = (f32x4){0.f, 0.f, 0.f, 0.f};
  }
  float lr1[4] = {0.f, 0.f, 0.f, 0.f};
  float lr2[4] = {0.f, 0.f, 0.f, 0.f};

  for (int k0 = 0; k0 < NTOK; k0 += KVB) {
    __syncthreads();
    // ---- stage K1,K2 (XOR-swizzled rows) and V^T tile
    #pragma unroll
    for (int i = 0; i < 4; i++) {
      int o = (t + 256 * i) * 16;
      int row = o >> 9, col = o & 511;
      int sw = o ^ ((row & 7) << 4);
      s16x8 v1 = *(const s16x8*)(K1b + (size_t)(k0 + row) * 512 + col);
      *(s16x8*)(smem + K1O + sw) = v1;
      s16x8 v2 = *(const s16x8*)(K2b + (size_t)(k0 + row) * 512 + col);
      *(s16x8*)(smem + K2O + sw) = v2;
    }
    #pragma unroll
    for (int i = 0; i < 4; i++) {
      int o = (t + 256 * i) * 16;
      int row = o >> 6, col = o & 63;            // 256 d-rows x 64B
      s16x8 v = *(const s16x8*)(Vtb + (size_t)row * 4608 + k0 * 2 + col);
      *(s16x8*)(smem + VO + row * 68 + col) = v;
    }
    __syncthreads();

    // ---- S phase + no-max softmax, P -> LDS (fp32)
    #pragma unroll
    for (int p = 0; p < 2; p++) {
      const char* Kb = smem + (p ? K2O : K1O);
      float* lr = p ? lr2 : lr1;
      #pragma unroll
      for (int n = 0; n < 2; n++) {
        f32x4 s = (f32x4){0.f, 0.f, 0.f, 0.f};
        int tok = n * 16 + c;
        #pragma unroll
        for (int dc = 0; dc < 8; dc++) {
          int addr = (tok * 512 + dc * 64 + g * 16) ^ ((tok & 7) << 4);
          s16x8 kf = *(const s16x8*)(Kb + addr);
          s = __builtin_amdgcn_mfma_f32_16x16x32_bf16(qh[dc], kf, s, 0, 0, 0);
          s = __builtin_amdgcn_mfma_f32_16x16x32_bf16(ql[dc], kf, s, 0, 0, 0);
        }
        #pragma unroll
        for (int j = 0; j < 4; j++) {
          float pv = exp2f(s[j] - BIAS2);
          lr[j] += pv;
          // P row = g*4+j, col = tok ; row stride 36 floats
          *(float*)(smem + PO + (((w * 2 + p) * 16 + g * 4 + j) * 36 + n * 16 + c) * 4) = pv;
        }
      }
    }

    // ---- P -> bf16 A-fragments (wave-local LDS round trip)
    s16x8 pa[2];
    #pragma unroll
    for (int p = 0; p < 2; p++) {
      const char* Pb = smem + PO + ((w * 2 + p) * 16 + c) * 144 + g * 32;
      f32x4 plo = *(const f32x4*)Pb;
      f32x4 phi = *(const f32x4*)(Pb + 16);
      s16x8 v;
      #pragma unroll
      for (int j = 0; j < 4; j++) {
        v[j]     = (short)f2bf(plo[j]);
        v[4 + j] = (short)f2bf(phi[j]);
      }
      pa[p] = v;
    }

    // ---- PV phase
    #pragma unroll
    for (int dt = 0; dt < 16; dt++) {
      s16x8 vf = *(const s16x8*)(smem + VO + (dt * 16 + c) * 68 + g * 16);
      a1[dt] = __builtin_amdgcn_mfma_f32_16x16x32_bf16(pa[0], vf, a1[dt], 0, 0, 0);
      a2[dt] = __builtin_amdgcn_mfma_f32_16x16x32_bf16(pa[1], vf, a2[dt], 0, 0, 0);
    }
  }

  // ---- reduce row sums across the 16 col-lanes (same g group)
  #pragma unroll
  for (int j = 0; j < 4; j++) {
    #pragma unroll
    for (int off = 1; off < 16; off <<= 1) {
      lr1[j] += __shfl_xor(lr1[j], off);
      lr2[j] += __shfl_xor(lr2[j], off);
    }
  }
  const float mu = mup[0];
  const float cw1 = 0.5f / (0.5f + mu);
  const float cw2 = mu / (0.5f + mu);

  __syncthreads();   // all LDS compute reads done; overlay att tile
  #pragma unroll
  for (int j = 0; j < 4; j++) {
    float r1 = cw1 / lr1[j], r2 = cw2 / lr2[j];
    #pragma unroll
    for (int dt = 0; dt < 16; dt++) {
      int row = w * 16 + g * 4 + j, col = dt * 16 + c;
      *(float*)(smem + (row * 257 + col) * 4) = a1[dt][j] * r1 + a2[dt][j] * r2;
    }
  }
  __syncthreads();

  // ---- epilogue: out[b][d][q] = qry + att, coalesced over q
  const int tq = t & 63, dr = t >> 6;
  #pragma unroll
  for (int i = 0; i < 64; i++) {
    int d = dr * 64 + i;
    size_t gi = bo + (size_t)d * NTOK + q0 + tq;
    out[gi] = qry[gi] + *(const float*)(smem + (tq * 257 + d) * 4);
  }
}

extern "C" void kernel_launch(void* const* d_in, const int* in_sizes, int n_in,
                              void* d_out, int out_size, void* d_ws, size_t ws_size,
                              hipStream_t stream) {
  const float* qry  = (const float*)d_in[0];
  const float* mask = (const float*)d_in[1];
  const float* fts  = (const float*)d_in[2];
  const float* Wq   = (const float*)d_in[3];
  const float* Wk   = (const float*)d_in[4];
  const float* Wv   = (const float*)d_in[5];
  const float* mu   = (const float*)d_in[6];
  float* out = (float*)d_out;

  const size_t SZ = (size_t)BB * CC * NTOK;
  unsigned short* Qhw = (unsigned short*)d_ws;
  unsigned short* Qlw = Qhw + SZ;
  unsigned short* K1w = Qhw + 2 * SZ;
  unsigned short* K2w = Qhw + 3 * SZ;
  unsigned short* Vtw = Qhw + 4 * SZ;

  dim3 pg(NTOK / 64, CC / 64, BB);
  proj_kernel<0><<<pg, 256, 0, stream>>>(qry,  Wq, Qhw, Qlw);
  proj_kernel<1><<<pg, 256, 0, stream>>>(fts,  Wk, K1w, nullptr);
  proj_kernel<1><<<pg, 256, 0, stream>>>(mask, Wk, K2w, nullptr);
  proj_kernel<2><<<pg, 256, 0, stream>>>(fts,  Wv, Vtw, nullptr);

  attn_kernel<<<BB * (NTOK / 64), 256, 0, stream>>>(Qhw, Qlw, K1w, K2w, Vtw, qry, mu, out);
}